// Round 4
// baseline (8387.797 us; speedup 1.0000x reference)
//
#include <hip/hip_runtime.h>

// ---------------------------------------------------------------------------
// GRU (T=256 steps, B=1024, IN=128, H=256) + per-timestep BatchNorm, MI355X.
// R3->R4: 2-way gate-column split across 128 blocks (512 thr, 2 waves/SIMD,
// VGPR cap 256) so ALL weights fit in registers (R3's 1024-thr block capped
// VGPRs at 128 -> compiler re-streamed 576 KB/step/CU from L2 = the 9.6
// us/step). Per-step 4 KB h-slice exchange with partner block (b^64) via L2
// + release/acquire flags. y-GEMM duplicated per pair (saves 2nd sync).
// Stats moved out of the hot loop into a separate pass (kills the per-step
// 64-way atomic contention drain).
// ---------------------------------------------------------------------------

typedef _Float16 half8 __attribute__((ext_vector_type(8)));
typedef float floatx4 __attribute__((ext_vector_type(4)));

#define EPS_BN 1e-5f

// ws layout (bytes):
//   [0,       589824)   wg_pack: 16 col-groups x 36 tiles x 64 lanes x 16B
//   [589824,  655360)   wl_pack: 64 tiles x 64 lanes x 16B
//   [655360,  659456)   bias_pack: 256 x float4 (br, bz, b_ih_n, b_hh_n)
//   [659456,  921600)   stats: 256 t x 128 c x {mean, scale} fp32
//   [921600,  925696)   flags: 128 x uint (monotonic step counters) [memset 0]
//   [925696, 1974272)   xch: 2 parity x 128 blocks x 4096 B h-slice frags
#define WS_WG 0
#define WS_WL 589824
#define WS_BIAS 655360
#define WS_STATS 659456
#define WS_FLAGS 921600
#define WS_XCH 925696

static __device__ __forceinline__ unsigned short f2h(float f) {
    union { _Float16 h; unsigned short u; } v;
    v.h = (_Float16)f;                      // v_cvt_f16_f32, RNE
    return v.u;
}
static __device__ __forceinline__ half8 as_h8(uint4 v) {
    union { uint4 u; half8 h; } x; x.u = v; return x.h;
}
static __device__ __forceinline__ float sigm(float x) {
    return 1.0f / (1.0f + __expf(-x));
}
static __device__ __forceinline__ float tanh_fast(float x) {
    return 1.0f - 2.0f / (__expf(2.0f * x) + 1.0f);
}

// ---------------------------------------------------------------------------
// Pack kernel: weights fp32 -> fp16 MFMA-B-fragment-linear layout; biases.
// B-frag for 16x16x32: lane l holds B[n = n0 + (l&15)][k = k0 + (l>>4)*8 + j].
// wg tile order per col-group cg(0..15): [gate r,z,n][kt 0..11]; col n =
// g*256 + cg*16 + (l&15). K order: k<128 -> W_ih (x), k>=128 -> W_hh (h).
// ---------------------------------------------------------------------------
__global__ void pack_kernel(const float* __restrict__ W_ih, const float* __restrict__ W_hh,
                            const float* __restrict__ W_lin, const float* __restrict__ b_ih,
                            const float* __restrict__ b_hh,
                            uint4* __restrict__ wg, uint4* __restrict__ wl,
                            float4* __restrict__ biasp)
{
    int i = blockIdx.x * 256 + threadIdx.x;
    if (i < 36864) {                       // 576 wg tiles x 64 lanes
        int lane = i & 63, tile = i >> 6;
        int cg = tile / 36, rem = tile - cg * 36;
        int g = rem / 12, kt = rem - g * 12;
        int n = g * 256 + (cg << 4) + (lane & 15);
        int k0 = (kt << 5) + ((lane >> 4) << 3);
        const float* p = (k0 < 128) ? (W_ih + n * 128 + k0)
                                    : (W_hh + n * 256 + (k0 - 128));
        unsigned short h[8];
        #pragma unroll
        for (int j = 0; j < 8; ++j) h[j] = f2h(p[j]);
        uint4 v;
        v.x = (unsigned)h[0] | ((unsigned)h[1] << 16);
        v.y = (unsigned)h[2] | ((unsigned)h[3] << 16);
        v.z = (unsigned)h[4] | ((unsigned)h[5] << 16);
        v.w = (unsigned)h[6] | ((unsigned)h[7] << 16);
        wg[i] = v;
    } else if (i < 40960) {                // 64 wl tiles x 64 lanes
        int i2 = i - 36864;
        int lane = i2 & 63, tile = i2 >> 6;        // tile = nt*8 + kt
        int n = (tile >> 3) * 16 + (lane & 15);    // 0..127
        int k0 = ((tile & 7) << 5) + ((lane >> 4) << 3);
        const float* p = W_lin + n * 256 + k0;
        unsigned short h[8];
        #pragma unroll
        for (int j = 0; j < 8; ++j) h[j] = f2h(p[j]);
        uint4 v;
        v.x = (unsigned)h[0] | ((unsigned)h[1] << 16);
        v.y = (unsigned)h[2] | ((unsigned)h[3] << 16);
        v.z = (unsigned)h[4] | ((unsigned)h[5] << 16);
        v.w = (unsigned)h[6] | ((unsigned)h[7] << 16);
        wl[i2] = v;
    } else if (i < 41216) {
        int cb = i - 40960;                // 0..255
        biasp[cb] = make_float4(b_ih[cb] + b_hh[cb],
                                b_ih[256 + cb] + b_hh[256 + cb],
                                b_ih[512 + cb], b_hh[512 + cb]);
    }
}

// ---------------------------------------------------------------------------
// Recurrence kernel: 128 blocks x 512 threads (8 waves, 2 waves/SIMD).
// Block b: batch rows (b&63)*16 .. +16, gate-col half hf=b>>6
// (cols hf*128 .. +128). Partner b^64 owns the other half; per-step 4 KB
// h-fragment exchange through L2 with release/acquire + monotonic flags.
// All weight B-fragments register-resident (~230 VGPR < 256 cap).
// LDS: double-buffered [x|h] A-frag buffer 2 x 12 x 64 x 16B = 24 KB.
// ---------------------------------------------------------------------------
__global__ __launch_bounds__(512, 2) void gru_kernel(
    const float* __restrict__ inputs,
    const float* __restrict__ hidden,
    const uint4* __restrict__ wg,
    const uint4* __restrict__ wl,
    const float4* __restrict__ biasp,
    const float* __restrict__ b_lin,
    float* __restrict__ out,
    uint4* __restrict__ xch,
    unsigned* __restrict__ flags)
{
    __shared__ uint4 lds_xh[2 * 12 * 64];

    const int tid = threadIdx.x;
    const int lane = tid & 63;
    const int w = tid >> 6;            // wave 0..7
    const int quad = lane >> 4;        // 0..3 (rows quad*4+d)
    const int nc = lane & 15;          // col within wave's 16
    const int b  = blockIdx.x;
    const int hf = b >> 6;             // column half 0/1
    const int partner = b ^ 64;
    const int r0 = (b & 63) << 4;      // first batch row

    const int cg = (hf << 3) + w;      // global col-group 0..15
    const int c  = (cg << 4) + nc;     // gate col 0..255
    const float4 bias = biasp[c];

    // ---- weights: fully register-resident (loaded once)
    half8 wgB[36];                     // 144 VGPRs
    {
        const uint4* wgw = wg + cg * 36 * 64;
        #pragma unroll
        for (int i = 0; i < 36; ++i) wgB[i] = as_h8(wgw[i * 64 + lane]);
    }
    half8 wlB[8];                      // 32 VGPRs: y-cols w*16..w*16+16, full K
    #pragma unroll
    for (int kt = 0; kt < 8; ++kt) wlB[kt] = as_h8(wl[(w * 8 + kt) * 64 + lane]);
    const float blc = b_lin[(w << 4) + nc];

    // fp32 master hidden state: rows quad*4+d, col c
    float hreg[4];
    #pragma unroll
    for (int d = 0; d < 4; ++d)
        hreg[d] = hidden[(r0 + (quad << 2) + d) * 256 + c];

    // frag addressing (A-frag 16x16x32: value A[m][k]: tile kt=k>>5, k'=k&31,
    // frag lane = (k'>>3)*16 + m, j = k'&7; ushort idx = (kt*64+lane_f)*8+j)
    unsigned short* lds_u16 = (unsigned short*)lds_xh;
    const int kp = ((w & 1) << 4) + nc;            // k' within tile (h and y)
    const int kt_h = 4 + (hf << 2) + (w >> 1);     // own h tile 4..11
    const int lane_f = ((kp >> 3) << 4) + (quad << 2);
    const int hfrag_base = ((kt_h * 64 + lane_f) << 3) + (kp & 7);
    const int xfrag_base = (((w >> 1) * 64 + lane_f) << 3) + (kp & 7);
    // within-slice (4 tiles) base for the exchange buffer
    const int hx_base = (((w >> 1) * 64 + lane_f) << 3) + (kp & 7);

    unsigned short* xch_u16 = (unsigned short*)xch;
    const int pdst = (4 + ((1 - hf) << 2)) << 6;   // partner tiles' uint4 offset

    // init h-fragments (FULL h, both halves, from global hidden)
    for (int idx = tid; idx < 2048; idx += 512) {  // u32 granularity
        int ktl = idx >> 8;                        // 0..7
        int rem = idx & 255;
        int lf = rem >> 2, jg = rem & 3;
        int m = lf & 15, khi = lf >> 4;
        int hc = ktl * 32 + khi * 8 + jg * 2;
        const float* p = hidden + (r0 + m) * 256 + hc;
        unsigned pk = (unsigned)f2h(p[0]) | ((unsigned)f2h(p[1]) << 16);
        ((unsigned*)lds_xh)[((4 + ktl) * 64 + lf) * 4 + jg] = pk;
    }
    // init x-fragments from inputs [1024,128] fp32
    for (int idx = tid; idx < 1024; idx += 512) {
        int kt = idx >> 8;                         // 0..3
        int lf = (idx >> 2) & 63, jg = idx & 3;
        int m = lf & 15;
        int k0 = (kt << 5) + ((lf >> 4) << 3) + (jg << 1);
        const float* p = inputs + (r0 + m) * 128 + k0;
        unsigned pk = (unsigned)f2h(p[0]) | ((unsigned)f2h(p[1]) << 16);
        ((unsigned*)lds_xh)[((kt << 6) + lf) * 4 + jg] = pk;
    }
    __syncthreads();

    int po = 0;
    for (int t = 0; t < 256; ++t) {
        const int qo = po ^ 768;
        const int qo16 = qo << 3;

        // ---- P1: gate GEMMs from buf[p] (x kt 0..3 | h kt 4..11)
        floatx4 ar = {0.f, 0.f, 0.f, 0.f};
        floatx4 az = {0.f, 0.f, 0.f, 0.f};
        floatx4 ain = {0.f, 0.f, 0.f, 0.f};
        floatx4 ahn = {0.f, 0.f, 0.f, 0.f};
        #pragma unroll
        for (int kt = 0; kt < 12; ++kt) {
            half8 A = as_h8(lds_xh[po + (kt << 6) + lane]);
            ar = __builtin_amdgcn_mfma_f32_16x16x32_f16(A, wgB[kt], ar, 0, 0, 0);
            az = __builtin_amdgcn_mfma_f32_16x16x32_f16(A, wgB[12 + kt], az, 0, 0, 0);
            if (kt < 4)
                ain = __builtin_amdgcn_mfma_f32_16x16x32_f16(A, wgB[24 + kt], ain, 0, 0, 0);
            else
                ahn = __builtin_amdgcn_mfma_f32_16x16x32_f16(A, wgB[24 + kt], ahn, 0, 0, 0);
        }

        // ---- P2: elementwise GRU update; h-frags -> buf[q] local + xch slice
        unsigned short* xslice = xch_u16 + (((t & 1) * 128 + b) << 11); // 2048 u16
        #pragma unroll
        for (int d = 0; d < 4; ++d) {
            float rr = sigm(ar[d] + bias.x);
            float zz = sigm(az[d] + bias.y);
            float nn = tanh_fast(ain[d] + bias.z + rr * (ahn[d] + bias.w));
            float hnew = (1.0f - zz) * nn + zz * hreg[d];
            hreg[d] = hnew;
            unsigned short hu = f2h(hnew);
            lds_u16[qo16 + hfrag_base + (d << 3)] = hu;
            xslice[hx_base + (d << 3)] = hu;
        }
        __threadfence();       // publish xch writes at agent scope
        __syncthreads();       // B0: all threads' h writes fenced
        if (tid == 0)
            __hip_atomic_store(&flags[b], (unsigned)(t + 1),
                               __ATOMIC_RELEASE, __HIP_MEMORY_SCOPE_AGENT);

        // ---- wait for partner h-slice, copy into buf[q] (waves 0..3)
        if (tid < 256) {
            const unsigned tgt = (unsigned)(t + 1);
            while (__hip_atomic_load(&flags[partner], __ATOMIC_ACQUIRE,
                                     __HIP_MEMORY_SCOPE_AGENT) < tgt)
                __builtin_amdgcn_s_sleep(1);
            const uint4* src = xch + (((t & 1) * 128 + partner) << 8);
            lds_xh[qo + pdst + tid] = src[tid];
        }
        __syncthreads();       // B1: full h(t+1) frags in buf[q]

        // ---- P3: y = h_new @ W_lin^T + b_lin (full y, all 8 waves),
        //      y -> x-frag(q); store out only for own column half.
        floatx4 ay = {0.f, 0.f, 0.f, 0.f};
        #pragma unroll
        for (int kt = 0; kt < 8; ++kt) {
            half8 A = as_h8(lds_xh[qo + ((4 + kt) << 6) + lane]);
            ay = __builtin_amdgcn_mfma_f32_16x16x32_f16(A, wlB[kt], ay, 0, 0, 0);
        }
        float* orow = out + ((size_t)t << 17) + (size_t)((r0 + (quad << 2)) << 7)
                      + (w << 4) + nc;
        #pragma unroll
        for (int d = 0; d < 4; ++d) {
            float y = ay[d] + blc;
            lds_u16[qo16 + xfrag_base + (d << 3)] = f2h(y);
            if ((w >> 2) == hf) orow[d << 7] = y;
        }
        __syncthreads();       // B2: x-frag(q) ready for next P1
        po = qo;
    }
}

// ---------------------------------------------------------------------------
// Stat kernel: per-(t,c) mean + rsqrt(var+eps) from out. Block per t.
// ---------------------------------------------------------------------------
__global__ void stat_kernel(const float* __restrict__ out, float* __restrict__ stats)
{
    __shared__ float sh1[256], sh2[256];
    int t = blockIdx.x, tid = threadIdx.x;
    int c = tid & 127, rh = tid >> 7;
    const float* p = out + ((size_t)t << 17) + ((size_t)rh << 16) + c;
    float a = 0.f, s = 0.f;
    #pragma unroll 8
    for (int r = 0; r < 512; ++r) { float v = p[(size_t)r << 7]; a += v; s += v * v; }
    sh1[tid] = a; sh2[tid] = s;
    __syncthreads();
    if (tid < 128) {
        float su = sh1[tid] + sh1[tid + 128];
        float sq = sh2[tid] + sh2[tid + 128];
        float mean = su * (1.0f / 1024.0f);
        float var = sq * (1.0f / 1024.0f) - mean * mean;
        stats[((t << 7) + tid) * 2]     = mean;
        stats[((t << 7) + tid) * 2 + 1] = rsqrtf(var + EPS_BN);
    }
}

// ---------------------------------------------------------------------------
// Normalize kernel: in-place batchnorm on d_out using {mean, scale}.
// ---------------------------------------------------------------------------
__global__ void norm_kernel(float* __restrict__ out, const float* __restrict__ stats)
{
    __shared__ float smean[128], sscale[128];
    int t = blockIdx.x >> 2, q = blockIdx.x & 3;
    int tid = threadIdx.x;
    if (tid < 128) {
        int si = ((t << 7) + tid) << 1;
        smean[tid]  = stats[si];
        sscale[tid] = stats[si + 1];
    }
    __syncthreads();
    float4* p = (float4*)(out + ((size_t)t << 17) + ((size_t)q << 15));
    for (int i = tid; i < 8192; i += 256) {      // 256 rows x 32 float4
        int cc = (i & 31) << 2;
        float4 v = p[i];
        v.x = (v.x - smean[cc])     * sscale[cc];
        v.y = (v.y - smean[cc + 1]) * sscale[cc + 1];
        v.z = (v.z - smean[cc + 2]) * sscale[cc + 2];
        v.w = (v.w - smean[cc + 3]) * sscale[cc + 3];
        p[i] = v;
    }
}

extern "C" void kernel_launch(void* const* d_in, const int* in_sizes, int n_in,
                              void* d_out, int out_size, void* d_ws, size_t ws_size,
                              hipStream_t stream) {
    (void)in_sizes; (void)n_in; (void)out_size; (void)ws_size;
    const float* inputs = (const float*)d_in[0];
    const float* hidden = (const float*)d_in[1];
    const float* W_ih   = (const float*)d_in[2];
    const float* b_ih   = (const float*)d_in[3];
    const float* W_hh   = (const float*)d_in[4];
    const float* b_hh   = (const float*)d_in[5];
    const float* W_lin  = (const float*)d_in[6];
    const float* b_lin  = (const float*)d_in[7];

    char* ws = (char*)d_ws;
    uint4*    wg    = (uint4*)(ws + WS_WG);
    uint4*    wl    = (uint4*)(ws + WS_WL);
    float4*   biasp = (float4*)(ws + WS_BIAS);
    float*    stats = (float*)(ws + WS_STATS);
    unsigned* flags = (unsigned*)(ws + WS_FLAGS);
    uint4*    xch   = (uint4*)(ws + WS_XCH);

    hipMemsetAsync(flags, 0, 4096, stream);
    pack_kernel<<<161, 256, 0, stream>>>(W_ih, W_hh, W_lin, b_ih, b_hh, wg, wl, biasp);
    gru_kernel<<<128, 512, 0, stream>>>(inputs, hidden, wg, wl, biasp, b_lin,
                                        (float*)d_out, xch, flags);
    stat_kernel<<<256, 256, 0, stream>>>((const float*)d_out, stats);
    norm_kernel<<<1024, 256, 0, stream>>>((float*)d_out, stats);
}

// Round 5
// 1518.536 us; speedup vs baseline: 5.5236x; 5.5236x over previous
//
#include <hip/hip_runtime.h>

// ---------------------------------------------------------------------------
// GRU (T=256, B=1024, IN=128, H=256) + per-step BatchNorm, MI355X.
// R4->R5: (1) x-GEMM folded into weights: for t>=1 gates = h @ Wc^T (K=256,
//   1024 cols; Wc = [W_ih@W_lin + W_hh | W_ihn@W_lin | W_hhn], fp32 fold on
//   device) -> ONE barrier/step, no y in the recurrence. y reconstructed
//   post-hoc by a parallel GEMM over all t (h stored fp16 in-place in d_out).
// (2) weights forced register-resident with asm-pin (plain loads were
//   rematerialized by the compiler in R3/R4 -> VGPR_Count stayed 64/116).
//   Per wave: 20 tiles pinned VGPR + 2 LDS + 10 streamed/step (prefetch q).
// (3) cross-block exchange removed (R4: 32 us/step from cross-XCD fences).
// ---------------------------------------------------------------------------

typedef _Float16 half8 __attribute__((ext_vector_type(8)));
typedef float floatx4 __attribute__((ext_vector_type(4)));
typedef unsigned uintx4 __attribute__((ext_vector_type(4)));

#define EPS_BN 1e-5f

// ws layout (bytes):
//   [0,       524288)   wc: folded gate weights, 16 waves x 32 tiles x 1 KB
//   [524288, 1114112)   w0: step-0 weights (R3 layout), 16 x 36 tiles x 1 KB
//   [1114112,1179648)   wl: W_lin B-frags, 64 tiles x 1 KB
//   [1179648,1183744)   bias0: 256 x float4 (b_r, b_z, b_ihn, b_hhn)
//   [1183744,1187840)   bc: 256 x float4 folded biases
//   [1187840,1449984)   stats: 256 t x 128 c x {sum, sumsq} fp32 (memset 0)
#define WS_WC 0
#define WS_W0 524288
#define WS_WL 1114112
#define WS_B0 1179648
#define WS_BC 1183744
#define WS_ST 1187840

static __device__ __forceinline__ unsigned short f2h(float f) {
    union { _Float16 h; unsigned short u; } v;
    v.h = (_Float16)f;                      // v_cvt_f16_f32, RNE
    return v.u;
}
static __device__ __forceinline__ half8 as_h8(uint4 v) {
    union { uint4 u; half8 h; } x; x.u = v; return x.h;
}
// load + opaque-touch: compiler cannot rematerialize the load, so the value
// stays VGPR-resident across the t-loop (the R3/R4 failure mode).
static __device__ __forceinline__ half8 ld_pin(const uint4* p) {
    uintx4 v = *(const uintx4*)p;
    asm volatile("" : "+v"(v));
    union { uintx4 u; half8 h; } x; x.u = v; return x.h;
}
static __device__ __forceinline__ float sigm(float x) {
    return 1.0f / (1.0f + __expf(-x));
}
static __device__ __forceinline__ float tanh_fast(float x) {
    return 1.0f - 2.0f / (__expf(2.0f * x) + 1.0f);
}

// ---------------------------------------------------------------------------
// pack_w0: original weights -> fp16 B-frag tiles (R3-verified layout) + wl
// + bias0. B-frag 16x16x32: lane l holds B[n0+(l&15)][k0+(l>>4)*8+j].
// ---------------------------------------------------------------------------
__global__ void pack_w0_kernel(const float* __restrict__ W_ih, const float* __restrict__ W_hh,
                               const float* __restrict__ W_lin, const float* __restrict__ b_ih,
                               const float* __restrict__ b_hh,
                               uint4* __restrict__ w0, uint4* __restrict__ wl,
                               float4* __restrict__ bias0)
{
    int i = blockIdx.x * 256 + threadIdx.x;
    if (i < 36864) {                       // 576 w0 tiles x 64 lanes
        int lane = i & 63, tile = i >> 6;
        int w = tile / 36, rem = tile - w * 36;
        int g = rem / 12, kt = rem - g * 12;
        int n = g * 256 + (w << 4) + (lane & 15);
        int k0 = (kt << 5) + ((lane >> 4) << 3);
        const float* p = (k0 < 128) ? (W_ih + n * 128 + k0)
                                    : (W_hh + n * 256 + (k0 - 128));
        unsigned short h[8];
        #pragma unroll
        for (int j = 0; j < 8; ++j) h[j] = f2h(p[j]);
        uint4 v;
        v.x = (unsigned)h[0] | ((unsigned)h[1] << 16);
        v.y = (unsigned)h[2] | ((unsigned)h[3] << 16);
        v.z = (unsigned)h[4] | ((unsigned)h[5] << 16);
        v.w = (unsigned)h[6] | ((unsigned)h[7] << 16);
        w0[i] = v;
    } else if (i < 40960) {                // 64 wl tiles x 64 lanes
        int i2 = i - 36864;
        int lane = i2 & 63, tile = i2 >> 6;        // tile = nt*8 + kt
        int n = (tile >> 3) * 16 + (lane & 15);    // W_lin row = out col i
        int k0 = ((tile & 7) << 5) + ((lane >> 4) << 3);
        const float* p = W_lin + n * 256 + k0;
        unsigned short h[8];
        #pragma unroll
        for (int j = 0; j < 8; ++j) h[j] = f2h(p[j]);
        uint4 v;
        v.x = (unsigned)h[0] | ((unsigned)h[1] << 16);
        v.y = (unsigned)h[2] | ((unsigned)h[3] << 16);
        v.z = (unsigned)h[4] | ((unsigned)h[5] << 16);
        v.w = (unsigned)h[6] | ((unsigned)h[7] << 16);
        wl[i2] = v;
    } else if (i < 41216) {
        int cb = i - 40960;                // 0..255
        bias0[cb] = make_float4(b_ih[cb] + b_hh[cb],
                                b_ih[256 + cb] + b_hh[256 + cb],
                                b_ih[512 + cb], b_hh[512 + cb]);
    }
}

// ---------------------------------------------------------------------------
// pack_wc: folded weights (fp32 fold, fp16 round once) + folded biases.
// Wc groups per wave-colgroup w: g=0 r: W_ih_r@W_lin + W_hh_r
//                                g=1 z: likewise at +256
//                                g=2 in: W_ihn@W_lin
//                                g=3 hn: W_hhn
// bc[c] = (b_ih_r+b_hh_r+b_lin@W_ih_r, ..z.., b_ihn+b_lin@W_ihn, b_hhn)
// ---------------------------------------------------------------------------
__global__ void pack_wc_kernel(const float* __restrict__ W_ih, const float* __restrict__ W_hh,
                               const float* __restrict__ W_lin, const float* __restrict__ b_ih,
                               const float* __restrict__ b_hh, const float* __restrict__ b_lin,
                               uint4* __restrict__ wc, float4* __restrict__ bc)
{
    int i = blockIdx.x * 256 + threadIdx.x;
    if (i < 32768) {                       // 512 wc tiles x 64 lanes
        int lane = i & 63, tile = i >> 6;
        int w = tile >> 5, r = tile & 31;
        int g = r >> 3, kt = r & 7;
        int c = (w << 4) + (lane & 15);    // h-col 0..255
        int k0 = (kt << 5) + ((lane >> 4) << 3);
        float s[8];
        if (g == 3) {
            #pragma unroll
            for (int j = 0; j < 8; ++j) s[j] = W_hh[(512 + c) * 256 + k0 + j];
        } else {
            int row = g * 256 + c;
            const float* wi = W_ih + row * 128;
            #pragma unroll
            for (int j = 0; j < 8; ++j) s[j] = 0.0f;
            for (int ii = 0; ii < 128; ++ii) {
                float wv = wi[ii];
                const float* wrow = W_lin + ii * 256 + k0;
                #pragma unroll
                for (int j = 0; j < 8; ++j) s[j] += wv * wrow[j];
            }
            if (g < 2) {
                #pragma unroll
                for (int j = 0; j < 8; ++j) s[j] += W_hh[row * 256 + k0 + j];
            }
        }
        unsigned short h[8];
        #pragma unroll
        for (int j = 0; j < 8; ++j) h[j] = f2h(s[j]);
        uint4 v;
        v.x = (unsigned)h[0] | ((unsigned)h[1] << 16);
        v.y = (unsigned)h[2] | ((unsigned)h[3] << 16);
        v.z = (unsigned)h[4] | ((unsigned)h[5] << 16);
        v.w = (unsigned)h[6] | ((unsigned)h[7] << 16);
        wc[i] = v;
    } else if (i < 33024) {
        int c = i - 32768;
        float d0 = 0.f, d1 = 0.f, d2 = 0.f;
        for (int ii = 0; ii < 128; ++ii) {
            float bl = b_lin[ii];
            d0 += bl * W_ih[c * 128 + ii];
            d1 += bl * W_ih[(256 + c) * 128 + ii];
            d2 += bl * W_ih[(512 + c) * 128 + ii];
        }
        bc[c] = make_float4(b_ih[c] + b_hh[c] + d0,
                            b_ih[256 + c] + b_hh[256 + c] + d1,
                            b_ih[512 + c] + d2,
                            b_hh[512 + c]);
    }
}

// ---------------------------------------------------------------------------
// Recurrence: 64 blocks x 1024 thr (16 waves, 4/SIMD, 128-VGPR cap).
// Block owns 16 batch rows; wave w owns h-cols [w*16, w*16+16).
// t=0: gates from inputs/hidden with streamed w0 (once).
// t>=1: gates = h @ Wc^T, K=256, ONE barrier/step.
// h(t+1) stored fp16 into d_out bytes (slot t) for the post-hoc y-GEMM.
// LDS: h-frag dbuf 2x8 tiles (16 KB) + x-frag 4 tiles (4 KB, t=0 only)
//      + 2 LDS-resident Wc tiles/wave (32 KB) = 53 KB.
// ---------------------------------------------------------------------------
__global__ __launch_bounds__(1024, 4) void gru_kernel(
    const float* __restrict__ inputs,
    const float* __restrict__ hidden,
    const uint4* __restrict__ wc,
    const uint4* __restrict__ w0,
    const float4* __restrict__ bias0,
    const float4* __restrict__ bcp,
    float* __restrict__ out)
{
    __shared__ uint4 lds[1280 + 2048];   // buf0 512 | buf1 512 | xbuf 256 | wlds

    const int tid  = threadIdx.x;
    const int lane = tid & 63;
    const int w    = tid >> 6;           // wave 0..15
    const int quad = lane >> 4;
    const int nc   = lane & 15;
    const int r0   = blockIdx.x << 4;
    const int c    = (w << 4) + nc;
    const float4 bc = bcp[c];
    const uint4* wcw = wc + w * 32 * 64;

    // ---- pinned register tiles: r kt0-7, z kt0-7, in kt0-3 (20 tiles)
    half8 wr[8], wz[8], wi[4];
    #pragma unroll
    for (int kt = 0; kt < 8; ++kt) wr[kt] = ld_pin(&wcw[kt * 64 + lane]);
    #pragma unroll
    for (int kt = 0; kt < 8; ++kt) wz[kt] = ld_pin(&wcw[(8 + kt) * 64 + lane]);
    #pragma unroll
    for (int kt = 0; kt < 4; ++kt) wi[kt] = ld_pin(&wcw[(16 + kt) * 64 + lane]);

    // ---- LDS-resident tiles: in kt4,5 (one-time copy)
    lds[1280 + (w * 2 + 0) * 64 + lane] = wcw[20 * 64 + lane];
    lds[1280 + (w * 2 + 1) * 64 + lane] = wcw[21 * 64 + lane];

    // fp32 master hidden state
    float hreg[4];
    #pragma unroll
    for (int d = 0; d < 4; ++d)
        hreg[d] = hidden[(r0 + (quad << 2) + d) * 256 + c];

    // A-frag write addressing: A[m][k]: kt=k>>5, k'=k&31,
    // frag lane=(k'>>3)*16+m, j=k'&7; u16 idx=(kt*64+lane_f)*8+j
    unsigned short* lds_u16 = (unsigned short*)lds;
    const int kp = ((w & 1) << 4) + nc;
    const int lane_f = ((kp >> 3) << 4) + (quad << 2);
    const int hfb = (((w >> 1) * 64 + lane_f) << 3) + (kp & 7);

    // init h(0) frags -> buf0 tiles 0..7
    for (int idx = tid; idx < 2048; idx += 1024) {
        int ktl = idx >> 8;
        int rem = idx & 255;
        int lf = rem >> 2, jg = rem & 3;
        int m = lf & 15;
        int hc = ktl * 32 + (lf >> 4) * 8 + jg * 2;
        const float* p = hidden + (r0 + m) * 256 + hc;
        unsigned pk = (unsigned)f2h(p[0]) | ((unsigned)f2h(p[1]) << 16);
        ((unsigned*)lds)[(ktl * 64 + lf) * 4 + jg] = pk;
    }
    // init x frags -> xbuf (uint4 1024..1279)
    {
        int kt = tid >> 8, lf = (tid >> 2) & 63, jg = tid & 3;
        int m = lf & 15;
        int k0 = (kt << 5) + ((lf >> 4) << 3) + (jg << 1);
        const float* p = inputs + (r0 + m) * 128 + k0;
        unsigned pk = (unsigned)f2h(p[0]) | ((unsigned)f2h(p[1]) << 16);
        ((unsigned*)lds)[(1024 + (kt << 6) + lf) * 4 + jg] = pk;
    }
    __syncthreads();

    unsigned short* Hout = (unsigned short*)out;

    // ---- t = 0: original weights, streamed once from L2
    {
        const uint4* w0w = w0 + w * 36 * 64;
        floatx4 ar = {0.f,0.f,0.f,0.f}, az = {0.f,0.f,0.f,0.f};
        floatx4 ain = {0.f,0.f,0.f,0.f}, ahn = {0.f,0.f,0.f,0.f};
        #pragma unroll
        for (int kt = 0; kt < 12; ++kt) {
            half8 A = as_h8(kt < 4 ? lds[1024 + (kt << 6) + lane]
                                   : lds[((kt - 4) << 6) + lane]);
            ar = __builtin_amdgcn_mfma_f32_16x16x32_f16(A, as_h8(w0w[kt * 64 + lane]), ar, 0, 0, 0);
            az = __builtin_amdgcn_mfma_f32_16x16x32_f16(A, as_h8(w0w[(12 + kt) * 64 + lane]), az, 0, 0, 0);
            if (kt < 4)
                ain = __builtin_amdgcn_mfma_f32_16x16x32_f16(A, as_h8(w0w[(24 + kt) * 64 + lane]), ain, 0, 0, 0);
            else
                ahn = __builtin_amdgcn_mfma_f32_16x16x32_f16(A, as_h8(w0w[(24 + kt) * 64 + lane]), ahn, 0, 0, 0);
        }
        float4 b0 = bias0[c];
        #pragma unroll
        for (int d = 0; d < 4; ++d) {
            float rr = sigm(ar[d] + b0.x);
            float zz = sigm(az[d] + b0.y);
            float nn = tanh_fast(ain[d] + b0.z + rr * (ahn[d] + b0.w));
            float hnew = (1.0f - zz) * nn + zz * hreg[d];
            hreg[d] = hnew;
            unsigned short hu = f2h(hnew);
            lds_u16[4096 + hfb + (d << 3)] = hu;                         // buf1
            Hout[(((size_t)0 + r0 + (quad << 2) + d) << 8) + c] = hu;    // slot 0
        }
        __syncthreads();
    }

    const int wldsbase = 1280 + (w << 1) * 64;

    // streamed prefetch queue: hn tiles 24..27
    half8 q[4];
    #pragma unroll
    for (int j = 0; j < 4; ++j) q[j] = as_h8(wcw[(24 + j) * 64 + lane]);

    for (int t = 1; t < 256; ++t) {
        const int rb = (t & 1) << 9;              // read buf (uint4)
        const int wb16 = (((t + 1) & 1) << 9) << 3;
        floatx4 ar = {0.f,0.f,0.f,0.f}, az = {0.f,0.f,0.f,0.f};
        floatx4 ain = {0.f,0.f,0.f,0.f}, ahn = {0.f,0.f,0.f,0.f};
        half8 si6, si7;

        #pragma unroll
        for (int kt = 0; kt < 8; ++kt) {
            half8 A  = as_h8(lds[rb + (kt << 6) + lane]);
            half8 hh = q[kt & 3];
            // rotate queue: tile (24 + (kt+4)&7) — restores 24..27 for next t
            q[kt & 3] = as_h8(wcw[(24 + ((kt + 4) & 7)) * 64 + lane]);
            if (kt == 2) si6 = as_h8(wcw[22 * 64 + lane]);
            if (kt == 3) si7 = as_h8(wcw[23 * 64 + lane]);
            ar = __builtin_amdgcn_mfma_f32_16x16x32_f16(A, wr[kt], ar, 0, 0, 0);
            az = __builtin_amdgcn_mfma_f32_16x16x32_f16(A, wz[kt], az, 0, 0, 0);
            half8 bi = (kt < 4) ? wi[kt]
                     : (kt < 6) ? as_h8(lds[wldsbase + ((kt - 4) << 6) + lane])
                                : ((kt == 6) ? si6 : si7);
            ain = __builtin_amdgcn_mfma_f32_16x16x32_f16(A, bi, ain, 0, 0, 0);
            ahn = __builtin_amdgcn_mfma_f32_16x16x32_f16(A, hh, ahn, 0, 0, 0);
        }

        #pragma unroll
        for (int d = 0; d < 4; ++d) {
            float rr = sigm(ar[d] + bc.x);
            float zz = sigm(az[d] + bc.y);
            float nn = tanh_fast(ain[d] + bc.z + rr * (ahn[d] + bc.w));
            float hnew = (1.0f - zz) * nn + zz * hreg[d];
            hreg[d] = hnew;
            unsigned short hu = f2h(hnew);
            lds_u16[wb16 + hfb + (d << 3)] = hu;
            Hout[(((size_t)(t << 10)) + r0 + (quad << 2) + d << 8) + c] = hu;
        }
        __syncthreads();
    }
}

// ---------------------------------------------------------------------------
// y-GEMM: out[t,b,:] = H[t,b,:] @ W_lin^T + b_lin, fused BN partial sums.
// In-place over d_out: each block stages its own 16 H-rows (8 KB) to LDS
// first, then overwrites the exact same byte range with y (fp32).
// Grid 16384 = 256 t x 64 row-slices; 256 thr = 4 waves x 2 col-groups.
// ---------------------------------------------------------------------------
__global__ __launch_bounds__(256) void ygemm_kernel(
    const uint4* __restrict__ wl, const float* __restrict__ b_lin,
    float* __restrict__ out, float* __restrict__ stats)
{
    __shared__ unsigned short sh[16 * 264];    // +8 u16 pad per row
    const int tid = threadIdx.x;
    const int t = blockIdx.x >> 6;
    const int r0 = (blockIdx.x & 63) << 4;

    {   // stage H rows (coalesced 32 B/thread)
        int row = tid >> 4, seg = tid & 15;
        const uint4* src = (const uint4*)((const unsigned short*)out
                         + (((size_t)t << 10) + r0 + row) * 256) + (seg << 1);
        uint4 a = src[0], b = src[1];
        uint4* dst = (uint4*)(sh + row * 264 + (seg << 4));
        dst[0] = a; dst[1] = b;
    }
    __syncthreads();

    const int lane = tid & 63, w = tid >> 6;
    const int quad = lane >> 4, nc = lane & 15;
    const int m = lane & 15, khi = lane >> 4;

    half8 B0[8], B1[8];
    #pragma unroll
    for (int kt = 0; kt < 8; ++kt) {
        B0[kt] = as_h8(wl[(((w << 1) + 0) * 8 + kt) * 64 + lane]);
        B1[kt] = as_h8(wl[(((w << 1) + 1) * 8 + kt) * 64 + lane]);
    }
    floatx4 a0 = {0.f,0.f,0.f,0.f}, a1 = {0.f,0.f,0.f,0.f};
    #pragma unroll
    for (int kt = 0; kt < 8; ++kt) {
        half8 A = *(const half8*)(sh + m * 264 + (kt << 5) + (khi << 3));
        a0 = __builtin_amdgcn_mfma_f32_16x16x32_f16(A, B0[kt], a0, 0, 0, 0);
        a1 = __builtin_amdgcn_mfma_f32_16x16x32_f16(A, B1[kt], a1, 0, 0, 0);
    }
    #pragma unroll
    for (int g = 0; g < 2; ++g) {
        floatx4 acc = g ? a1 : a0;
        int i = (((w << 1) + g) << 4) + nc;
        float bl = b_lin[i];
        float s1 = 0.f, s2 = 0.f;
        float* orow = out + (((size_t)t << 10) + r0 + (quad << 2)) * 128 + i;
        #pragma unroll
        for (int d = 0; d < 4; ++d) {
            float y = acc[d] + bl;
            orow[(size_t)d << 7] = y;
            s1 += y; s2 += y * y;
        }
        s1 += __shfl_xor(s1, 16); s1 += __shfl_xor(s1, 32);
        s2 += __shfl_xor(s2, 16); s2 += __shfl_xor(s2, 32);
        if (lane < 16) {
            int si = ((t << 7) + (((w << 1) + g) << 4) + lane) << 1;
            atomicAdd(&stats[si], s1);
            atomicAdd(&stats[si + 1], s2);
        }
    }
}

// ---------------------------------------------------------------------------
// Normalize: in-place BN from raw sums. Biased variance, eps inside sqrt.
// ---------------------------------------------------------------------------
__global__ void norm_kernel(float* __restrict__ out, const float* __restrict__ stats)
{
    __shared__ float smean[128], sscale[128];
    int t = blockIdx.x >> 2, q = blockIdx.x & 3;
    int tid = threadIdx.x;
    if (tid < 128) {
        int si = ((t << 7) + tid) << 1;
        float mean = stats[si] * (1.0f / 1024.0f);
        float var = stats[si + 1] * (1.0f / 1024.0f) - mean * mean;
        smean[tid] = mean;
        sscale[tid] = rsqrtf(var + EPS_BN);
    }
    __syncthreads();
    float4* p = (float4*)(out + ((size_t)t << 17) + ((size_t)q << 15));
    for (int i = tid; i < 8192; i += 256) {
        int cc = (i & 31) << 2;
        float4 v = p[i];
        v.x = (v.x - smean[cc])     * sscale[cc];
        v.y = (v.y - smean[cc + 1]) * sscale[cc + 1];
        v.z = (v.z - smean[cc + 2]) * sscale[cc + 2];
        v.w = (v.w - smean[cc + 3]) * sscale[cc + 3];
        p[i] = v;
    }
}

extern "C" void kernel_launch(void* const* d_in, const int* in_sizes, int n_in,
                              void* d_out, int out_size, void* d_ws, size_t ws_size,
                              hipStream_t stream) {
    (void)in_sizes; (void)n_in; (void)out_size; (void)ws_size;
    const float* inputs = (const float*)d_in[0];
    const float* hidden = (const float*)d_in[1];
    const float* W_ih   = (const float*)d_in[2];
    const float* b_ih   = (const float*)d_in[3];
    const float* W_hh   = (const float*)d_in[4];
    const float* b_hh   = (const float*)d_in[5];
    const float* W_lin  = (const float*)d_in[6];
    const float* b_lin  = (const float*)d_in[7];

    char* ws = (char*)d_ws;
    uint4*  wcp   = (uint4*)(ws + WS_WC);
    uint4*  w0p   = (uint4*)(ws + WS_W0);
    uint4*  wlp   = (uint4*)(ws + WS_WL);
    float4* bias0 = (float4*)(ws + WS_B0);
    float4* bcp   = (float4*)(ws + WS_BC);
    float*  stats = (float*)(ws + WS_ST);

    hipMemsetAsync(stats, 0, 262144, stream);
    pack_w0_kernel<<<161, 256, 0, stream>>>(W_ih, W_hh, W_lin, b_ih, b_hh, w0p, wlp, bias0);
    pack_wc_kernel<<<129, 256, 0, stream>>>(W_ih, W_hh, W_lin, b_ih, b_hh, b_lin, wcp, bcp);
    gru_kernel<<<64, 1024, 0, stream>>>(inputs, hidden, wcp, w0p, bias0, bcp, (float*)d_out);
    ygemm_kernel<<<16384, 256, 0, stream>>>(wlp, b_lin, (float*)d_out, stats);
    norm_kernel<<<1024, 256, 0, stream>>>((float*)d_out, stats);
}

// Round 6
// 1063.775 us; speedup vs baseline: 7.8849x; 1.4275x over previous
//
#include <hip/hip_runtime.h>

// ---------------------------------------------------------------------------
// GRU (T=256, B=1024, IN=128, H=256) + per-step BatchNorm, MI355X.
// R5->R6: capacity-correct weight residency. 64 blocks x 512 thr (8 waves,
// 2/SIMD, 256-reg cap). Wave owns 2 col-groups (32 cols): 64 Wc tiles =
//   32 pinned in AGPRs (asm "+a": opaque + AGPR class -> allocator cannot
//     refetch; MFMA reads AGPR B natively on gfx950)  [r,z gates]
//   16 LDS-resident (128 KB)                          [in kt2-7, hn kt0-1]
//   16 streamed/step via opaque pointers (128 KB/CU)  [in kt0-1, hn kt2-7]
// R5's "+v" value-pin was defeated twice (VGPR_Count stayed 64): VGPR-class
// values are refetchable in the allocator's cost model; "a"-class is not.
// ---------------------------------------------------------------------------

typedef _Float16 half8 __attribute__((ext_vector_type(8)));
typedef float floatx4 __attribute__((ext_vector_type(4)));
typedef unsigned uintx4 __attribute__((ext_vector_type(4)));

#define EPS_BN 1e-5f

// ws layout (bytes):
//   [0,       524288)   wc: folded gate weights, 16 cgs x 32 tiles x 1 KB
//   [524288, 1114112)   w0: step-0 weights, 16 cgs x 36 tiles x 1 KB
//   [1114112,1179648)   wl: W_lin B-frags, 64 tiles x 1 KB
//   [1179648,1183744)   bias0: 256 x float4
//   [1183744,1187840)   bc: 256 x float4 folded biases
//   [1187840,1449984)   stats: 256 t x 128 c x {sum,sumsq} fp32 (memset 0)
#define WS_WC 0
#define WS_W0 524288
#define WS_WL 1114112
#define WS_B0 1179648
#define WS_BC 1183744
#define WS_ST 1187840

static __device__ __forceinline__ unsigned short f2h(float f) {
    union { _Float16 h; unsigned short u; } v;
    v.h = (_Float16)f;                      // v_cvt_f16_f32, RNE
    return v.u;
}
static __device__ __forceinline__ half8 as_h8(uint4 v) {
    union { uint4 u; half8 h; } x; x.u = v; return x.h;
}
// Load a 16B weight fragment and force it into AGPRs (opaque, non-remat).
static __device__ __forceinline__ half8 ld_agpr(const uint4* p) {
    uintx4 v = *(const uintx4*)p;
    asm volatile("; wpin" : "+a"(v));
    union { uintx4 u; half8 h; } x; x.u = v; return x.h;
}
static __device__ __forceinline__ float sigm(float x) {
    return 1.0f / (1.0f + __expf(-x));
}
static __device__ __forceinline__ float tanh_fast(float x) {
    return 1.0f - 2.0f / (__expf(2.0f * x) + 1.0f);
}
#define MFMA16(A, B, C) __builtin_amdgcn_mfma_f32_16x16x32_f16((A), (B), (C), 0, 0, 0)

// ---------------------------------------------------------------------------
// pack_w0: original weights -> fp16 B-frag tiles + wl + bias0. (R3-verified)
// B-frag 16x16x32: lane l holds B[n0+(l&15)][k0+(l>>4)*8+j].
// ---------------------------------------------------------------------------
__global__ void pack_w0_kernel(const float* __restrict__ W_ih, const float* __restrict__ W_hh,
                               const float* __restrict__ W_lin, const float* __restrict__ b_ih,
                               const float* __restrict__ b_hh,
                               uint4* __restrict__ w0, uint4* __restrict__ wl,
                               float4* __restrict__ bias0)
{
    int i = blockIdx.x * 256 + threadIdx.x;
    if (i < 36864) {                       // 576 w0 tiles x 64 lanes
        int lane = i & 63, tile = i >> 6;
        int w = tile / 36, rem = tile - w * 36;
        int g = rem / 12, kt = rem - g * 12;
        int n = g * 256 + (w << 4) + (lane & 15);
        int k0 = (kt << 5) + ((lane >> 4) << 3);
        const float* p = (k0 < 128) ? (W_ih + n * 128 + k0)
                                    : (W_hh + n * 256 + (k0 - 128));
        unsigned short h[8];
        #pragma unroll
        for (int j = 0; j < 8; ++j) h[j] = f2h(p[j]);
        uint4 v;
        v.x = (unsigned)h[0] | ((unsigned)h[1] << 16);
        v.y = (unsigned)h[2] | ((unsigned)h[3] << 16);
        v.z = (unsigned)h[4] | ((unsigned)h[5] << 16);
        v.w = (unsigned)h[6] | ((unsigned)h[7] << 16);
        w0[i] = v;
    } else if (i < 40960) {                // 64 wl tiles x 64 lanes
        int i2 = i - 36864;
        int lane = i2 & 63, tile = i2 >> 6;        // tile = nt*8 + kt
        int n = (tile >> 3) * 16 + (lane & 15);
        int k0 = ((tile & 7) << 5) + ((lane >> 4) << 3);
        const float* p = W_lin + n * 256 + k0;
        unsigned short h[8];
        #pragma unroll
        for (int j = 0; j < 8; ++j) h[j] = f2h(p[j]);
        uint4 v;
        v.x = (unsigned)h[0] | ((unsigned)h[1] << 16);
        v.y = (unsigned)h[2] | ((unsigned)h[3] << 16);
        v.z = (unsigned)h[4] | ((unsigned)h[5] << 16);
        v.w = (unsigned)h[6] | ((unsigned)h[7] << 16);
        wl[i2] = v;
    } else if (i < 41216) {
        int cb = i - 40960;
        bias0[cb] = make_float4(b_ih[cb] + b_hh[cb],
                                b_ih[256 + cb] + b_hh[256 + cb],
                                b_ih[512 + cb], b_hh[512 + cb]);
    }
}

// ---------------------------------------------------------------------------
// pack_wc: folded weights (fp32 fold, one fp16 round) + folded biases.
// tile idx = cg*32 + g*8 + kt; g: 0=r (W_ih_r@W_lin + W_hh_r), 1=z,
// 2=in (W_ihn@W_lin), 3=hn (W_hhn). (R5-verified)
// ---------------------------------------------------------------------------
__global__ void pack_wc_kernel(const float* __restrict__ W_ih, const float* __restrict__ W_hh,
                               const float* __restrict__ W_lin, const float* __restrict__ b_ih,
                               const float* __restrict__ b_hh, const float* __restrict__ b_lin,
                               uint4* __restrict__ wc, float4* __restrict__ bc)
{
    int i = blockIdx.x * 256 + threadIdx.x;
    if (i < 32768) {                       // 512 wc tiles x 64 lanes
        int lane = i & 63, tile = i >> 6;
        int w = tile >> 5, r = tile & 31;
        int g = r >> 3, kt = r & 7;
        int c = (w << 4) + (lane & 15);
        int k0 = (kt << 5) + ((lane >> 4) << 3);
        float s[8];
        if (g == 3) {
            #pragma unroll
            for (int j = 0; j < 8; ++j) s[j] = W_hh[(512 + c) * 256 + k0 + j];
        } else {
            int row = g * 256 + c;
            const float* wi = W_ih + row * 128;
            #pragma unroll
            for (int j = 0; j < 8; ++j) s[j] = 0.0f;
            for (int ii = 0; ii < 128; ++ii) {
                float wv = wi[ii];
                const float* wrow = W_lin + ii * 256 + k0;
                #pragma unroll
                for (int j = 0; j < 8; ++j) s[j] += wv * wrow[j];
            }
            if (g < 2) {
                #pragma unroll
                for (int j = 0; j < 8; ++j) s[j] += W_hh[row * 256 + k0 + j];
            }
        }
        unsigned short h[8];
        #pragma unroll
        for (int j = 0; j < 8; ++j) h[j] = f2h(s[j]);
        uint4 v;
        v.x = (unsigned)h[0] | ((unsigned)h[1] << 16);
        v.y = (unsigned)h[2] | ((unsigned)h[3] << 16);
        v.z = (unsigned)h[4] | ((unsigned)h[5] << 16);
        v.w = (unsigned)h[6] | ((unsigned)h[7] << 16);
        wc[i] = v;
    } else if (i < 33024) {
        int c = i - 32768;
        float d0 = 0.f, d1 = 0.f, d2 = 0.f;
        for (int ii = 0; ii < 128; ++ii) {
            float bl = b_lin[ii];
            d0 += bl * W_ih[c * 128 + ii];
            d1 += bl * W_ih[(256 + c) * 128 + ii];
            d2 += bl * W_ih[(512 + c) * 128 + ii];
        }
        bc[c] = make_float4(b_ih[c] + b_hh[c] + d0,
                            b_ih[256 + c] + b_hh[256 + c] + d1,
                            b_ih[512 + c] + d2,
                            b_hh[512 + c]);
    }
}

// ---------------------------------------------------------------------------
// Recurrence: 64 blocks x 512 thr (8 waves, 2/SIMD). Block owns 16 batch
// rows; wave w owns col-groups {w, w+8} (cols c0=w*16.., c1=128+w*16..).
// LDS (uint4 units): [0,1024) h-frag dbuf | [1024,1280) xbuf | [1280,9472)
// per-wave weight tiles (16/wave). One barrier per step.
// ---------------------------------------------------------------------------
__global__ __launch_bounds__(512, 2) void gru_kernel(
    const float* __restrict__ inputs,
    const float* __restrict__ hidden,
    const uint4* __restrict__ wc,
    const uint4* __restrict__ w0,
    const float4* __restrict__ bias0,
    const float4* __restrict__ bcp,
    float* __restrict__ out)
{
    __shared__ uint4 lds[9472];            // 151552 B

    const int tid  = threadIdx.x;
    const int lane = tid & 63;
    const int w    = tid >> 6;             // wave 0..7
    const int quad = lane >> 4;
    const int nc   = lane & 15;
    const int r0   = blockIdx.x << 4;
    const int c0   = (w << 4) + nc;
    const int c1   = 128 + c0;
    const float4 bc0 = bcp[c0];
    const float4 bc1 = bcp[c1];
    const uint4* wcw0 = wc + (size_t)w * 2048;        // 32 tiles * 64
    const uint4* wcw1 = wc + (size_t)(w + 8) * 2048;

    // ---- AGPR-pinned tiles: r kt0-7, z kt0-7 for both col-groups
    half8 wr0[8], wz0[8], wr1[8], wz1[8];
    #pragma unroll
    for (int kt = 0; kt < 8; ++kt) {
        wr0[kt] = ld_agpr(&wcw0[kt * 64 + lane]);
        wz0[kt] = ld_agpr(&wcw0[(8 + kt) * 64 + lane]);
        wr1[kt] = ld_agpr(&wcw1[kt * 64 + lane]);
        wz1[kt] = ld_agpr(&wcw1[(8 + kt) * 64 + lane]);
    }

    // ---- LDS-resident tiles: per cg, tiles 18..25 (in kt2-7, hn kt0-1)
    const int wbase = 1280 + (w << 10);
    #pragma unroll
    for (int i = 0; i < 8; ++i) {
        lds[wbase + (i << 6) + lane]       = wcw0[(18 + i) * 64 + lane];
        lds[wbase + 512 + (i << 6) + lane] = wcw1[(18 + i) * 64 + lane];
    }

    // fp32 master hidden state: rows quad*4+d; [0..3]=c0, [4..7]=c1
    float hreg[8];
    #pragma unroll
    for (int d = 0; d < 4; ++d) {
        hreg[d]     = hidden[(r0 + (quad << 2) + d) * 256 + c0];
        hreg[4 + d] = hidden[(r0 + (quad << 2) + d) * 256 + c1];
    }

    // A-frag write addressing: A[m][k]: kt=k>>5, k'=k&31,
    // frag lane=(k'>>3)*16+m, j=k'&7; u16 idx=(kt*64+lane_f)*8+j
    unsigned short* lds_u16 = (unsigned short*)lds;
    const int kp  = ((w & 1) << 4) + nc;
    const int lf  = ((kp >> 3) << 4) + (quad << 2);
    const int hfb0 = (((w >> 1) * 64 + lf) << 3) + (kp & 7);
    const int hfb1 = (((4 + (w >> 1)) * 64 + lf) << 3) + (kp & 7);

    // init h(0) frags -> buf0
    for (int idx = tid; idx < 2048; idx += 512) {
        int ktl = idx >> 8;
        int rem = idx & 255;
        int lfr = rem >> 2, jg = rem & 3;
        int m = lfr & 15;
        int hc = ktl * 32 + (lfr >> 4) * 8 + jg * 2;
        const float* p = hidden + (r0 + m) * 256 + hc;
        unsigned pk = (unsigned)f2h(p[0]) | ((unsigned)f2h(p[1]) << 16);
        ((unsigned*)lds)[(ktl * 64 + lfr) * 4 + jg] = pk;
    }
    // init x frags -> xbuf
    for (int idx = tid; idx < 1024; idx += 512) {
        int kt = idx >> 8, lfr = (idx >> 2) & 63, jg = idx & 3;
        int m = lfr & 15;
        int k0 = (kt << 5) + ((lfr >> 4) << 3) + (jg << 1);
        const float* p = inputs + (r0 + m) * 128 + k0;
        unsigned pk = (unsigned)f2h(p[0]) | ((unsigned)f2h(p[1]) << 16);
        ((unsigned*)lds)[(1024 + (kt << 6) + lfr) * 4 + jg] = pk;
    }
    __syncthreads();

    unsigned short* Hout = (unsigned short*)out;

    // ---- t = 0: K=384 on [x|h] with original w0 (streamed once)
    {
        #pragma unroll
        for (int g2 = 0; g2 < 2; ++g2) {
            const uint4* ww = w0 + (size_t)(g2 ? (w + 8) : w) * 2304;  // 36*64
            floatx4 ar = {0.f,0.f,0.f,0.f}, az = {0.f,0.f,0.f,0.f};
            floatx4 ain = {0.f,0.f,0.f,0.f}, ahn = {0.f,0.f,0.f,0.f};
            #pragma unroll
            for (int kt = 0; kt < 12; ++kt) {
                half8 A = as_h8(kt < 4 ? lds[1024 + (kt << 6) + lane]
                                       : lds[((kt - 4) << 6) + lane]);
                ar = MFMA16(A, as_h8(ww[kt * 64 + lane]), ar);
                az = MFMA16(A, as_h8(ww[(12 + kt) * 64 + lane]), az);
                if (kt < 4)
                    ain = MFMA16(A, as_h8(ww[(24 + kt) * 64 + lane]), ain);
                else
                    ahn = MFMA16(A, as_h8(ww[(24 + kt) * 64 + lane]), ahn);
            }
            const int cc = g2 ? c1 : c0;
            const int hfb = g2 ? hfb1 : hfb0;
            float4 b0 = bias0[cc];
            #pragma unroll
            for (int d = 0; d < 4; ++d) {
                float rr = sigm(ar[d] + b0.x);
                float zz = sigm(az[d] + b0.y);
                float nn = tanh_fast(ain[d] + b0.z + rr * (ahn[d] + b0.w));
                float hnew = (1.0f - zz) * nn + zz * hreg[(g2 << 2) + d];
                hreg[(g2 << 2) + d] = hnew;
                unsigned short hu = f2h(hnew);
                lds_u16[4096 + hfb + (d << 3)] = hu;      // buf1
                Hout[((size_t)(r0 + (quad << 2) + d) << 8) + cc] = hu;
            }
        }
        __syncthreads();
    }

    for (int t = 1; t < 256; ++t) {
        const int rb   = (t & 1) << 9;                 // read buf (uint4)
        const int wb16 = (((t + 1) & 1) << 9) << 3;    // write buf (u16)

        // opaque per-iteration pointers: streamed tiles cannot be hoisted
        const uint4* s0p = wcw0 + lane;
        const uint4* s1p = wcw1 + lane;
        asm("" : "+v"(s0p), "+v"(s1p));

        // streamed batch A: in kt0,1 (tiles 16,17) + hn kt2,3 (tiles 26,27)
        uint4 a_i0 = s0p[16 * 64], a_i1 = s0p[17 * 64];
        uint4 a_h2 = s0p[26 * 64], a_h3 = s0p[27 * 64];
        uint4 b_i0 = s1p[16 * 64], b_i1 = s1p[17 * 64];
        uint4 b_h2 = s1p[26 * 64], b_h3 = s1p[27 * 64];

        floatx4 ar0 = {0.f,0.f,0.f,0.f}, az0 = {0.f,0.f,0.f,0.f};
        floatx4 ai0 = {0.f,0.f,0.f,0.f}, ah0 = {0.f,0.f,0.f,0.f};
        floatx4 ar1 = {0.f,0.f,0.f,0.f}, az1 = {0.f,0.f,0.f,0.f};
        floatx4 ai1 = {0.f,0.f,0.f,0.f}, ah1 = {0.f,0.f,0.f,0.f};

        uint4 a_h4, a_h5, a_h6, a_h7, b_h4, b_h5, b_h6, b_h7;

        #pragma unroll
        for (int kt = 0; kt < 8; ++kt) {
            half8 A = as_h8(lds[rb + (kt << 6) + lane]);
            if (kt == 1) {                  // streamed batch B, part 1
                a_h4 = s0p[28 * 64]; b_h4 = s1p[28 * 64];
                a_h5 = s0p[29 * 64]; b_h5 = s1p[29 * 64];
            }
            if (kt == 3) {                  // streamed batch B, part 2
                a_h6 = s0p[30 * 64]; b_h6 = s1p[30 * 64];
                a_h7 = s0p[31 * 64]; b_h7 = s1p[31 * 64];
            }
            ar0 = MFMA16(A, wr0[kt], ar0);
            ar1 = MFMA16(A, wr1[kt], ar1);
            az0 = MFMA16(A, wz0[kt], az0);
            az1 = MFMA16(A, wz1[kt], az1);
            half8 Bi0 = (kt == 0) ? as_h8(a_i0) : (kt == 1) ? as_h8(a_i1)
                       : as_h8(lds[wbase + ((kt - 2) << 6) + lane]);
            half8 Bi1 = (kt == 0) ? as_h8(b_i0) : (kt == 1) ? as_h8(b_i1)
                       : as_h8(lds[wbase + 512 + ((kt - 2) << 6) + lane]);
            ai0 = MFMA16(A, Bi0, ai0);
            ai1 = MFMA16(A, Bi1, ai1);
            half8 Bh0 = (kt < 2)  ? as_h8(lds[wbase + ((6 + kt) << 6) + lane])
                       : (kt == 2) ? as_h8(a_h2) : (kt == 3) ? as_h8(a_h3)
                       : (kt == 4) ? as_h8(a_h4) : (kt == 5) ? as_h8(a_h5)
                       : (kt == 6) ? as_h8(a_h6) : as_h8(a_h7);
            half8 Bh1 = (kt < 2)  ? as_h8(lds[wbase + 512 + ((6 + kt) << 6) + lane])
                       : (kt == 2) ? as_h8(b_h2) : (kt == 3) ? as_h8(b_h3)
                       : (kt == 4) ? as_h8(b_h4) : (kt == 5) ? as_h8(b_h5)
                       : (kt == 6) ? as_h8(b_h6) : as_h8(b_h7);
            ah0 = MFMA16(A, Bh0, ah0);
            ah1 = MFMA16(A, Bh1, ah1);
        }

        const size_t obase = (size_t)t * 1024 + r0 + (quad << 2);
        #pragma unroll
        for (int d = 0; d < 4; ++d) {
            float rr = sigm(ar0[d] + bc0.x);
            float zz = sigm(az0[d] + bc0.y);
            float nn = tanh_fast(ai0[d] + bc0.z + rr * (ah0[d] + bc0.w));
            float hnew = (1.0f - zz) * nn + zz * hreg[d];
            hreg[d] = hnew;
            unsigned short hu = f2h(hnew);
            lds_u16[wb16 + hfb0 + (d << 3)] = hu;
            Hout[((obase + d) << 8) + c0] = hu;
        }
        #pragma unroll
        for (int d = 0; d < 4; ++d) {
            float rr = sigm(ar1[d] + bc1.x);
            float zz = sigm(az1[d] + bc1.y);
            float nn = tanh_fast(ai1[d] + bc1.z + rr * (ah1[d] + bc1.w));
            float hnew = (1.0f - zz) * nn + zz * hreg[4 + d];
            hreg[4 + d] = hnew;
            unsigned short hu = f2h(hnew);
            lds_u16[wb16 + hfb1 + (d << 3)] = hu;
            Hout[((obase + d) << 8) + c1] = hu;
        }
        __syncthreads();
    }
}

// ---------------------------------------------------------------------------
// y-GEMM: out[t,b,:] = H[t,b,:] @ W_lin^T + b_lin, fused BN partial sums.
// In-place over d_out (stages its 16 H-rows to LDS first). (R5-verified)
// ---------------------------------------------------------------------------
__global__ __launch_bounds__(256) void ygemm_kernel(
    const uint4* __restrict__ wl, const float* __restrict__ b_lin,
    float* __restrict__ out, float* __restrict__ stats)
{
    __shared__ unsigned short sh[16 * 264];
    const int tid = threadIdx.x;
    const int t = blockIdx.x >> 6;
    const int r0 = (blockIdx.x & 63) << 4;

    {
        int row = tid >> 4, seg = tid & 15;
        const uint4* src = (const uint4*)((const unsigned short*)out
                         + (((size_t)t << 10) + r0 + row) * 256) + (seg << 1);
        uint4 a = src[0], b = src[1];
        uint4* dst = (uint4*)(sh + row * 264 + (seg << 4));
        dst[0] = a; dst[1] = b;
    }
    __syncthreads();

    const int lane = tid & 63, w = tid >> 6;
    const int quad = lane >> 4, nc = lane & 15;
    const int m = lane & 15, khi = lane >> 4;

    half8 B0[8], B1[8];
    #pragma unroll
    for (int kt = 0; kt < 8; ++kt) {
        B0[kt] = as_h8(wl[(((w << 1) + 0) * 8 + kt) * 64 + lane]);
        B1[kt] = as_h8(wl[(((w << 1) + 1) * 8 + kt) * 64 + lane]);
    }
    floatx4 a0 = {0.f,0.f,0.f,0.f}, a1 = {0.f,0.f,0.f,0.f};
    #pragma unroll
    for (int kt = 0; kt < 8; ++kt) {
        half8 A = *(const half8*)(sh + m * 264 + (kt << 5) + (khi << 3));
        a0 = MFMA16(A, B0[kt], a0);
        a1 = MFMA16(A, B1[kt], a1);
    }
    #pragma unroll
    for (int g = 0; g < 2; ++g) {
        floatx4 acc = g ? a1 : a0;
        int i = (((w << 1) + g) << 4) + nc;
        float bl = b_lin[i];
        float s1 = 0.f, s2 = 0.f;
        float* orow = out + (((size_t)t << 10) + r0 + (quad << 2)) * 128 + i;
        #pragma unroll
        for (int d = 0; d < 4; ++d) {
            float y = acc[d] + bl;
            orow[(size_t)d << 7] = y;
            s1 += y; s2 += y * y;
        }
        s1 += __shfl_xor(s1, 16); s1 += __shfl_xor(s1, 32);
        s2 += __shfl_xor(s2, 16); s2 += __shfl_xor(s2, 32);
        if (lane < 16) {
            int si = ((t << 7) + (((w << 1) + g) << 4) + lane) << 1;
            atomicAdd(&stats[si], s1);
            atomicAdd(&stats[si + 1], s2);
        }
    }
}

// ---------------------------------------------------------------------------
// Normalize: in-place BN from raw sums. Biased variance, eps inside sqrt.
// ---------------------------------------------------------------------------
__global__ void norm_kernel(float* __restrict__ out, const float* __restrict__ stats)
{
    __shared__ float smean[128], sscale[128];
    int t = blockIdx.x >> 2, q = blockIdx.x & 3;
    int tid = threadIdx.x;
    if (tid < 128) {
        int si = ((t << 7) + tid) << 1;
        float mean = stats[si] * (1.0f / 1024.0f);
        float var = stats[si + 1] * (1.0f / 1024.0f) - mean * mean;
        smean[tid] = mean;
        sscale[tid] = rsqrtf(var + EPS_BN);
    }
    __syncthreads();
    float4* p = (float4*)(out + ((size_t)t << 17) + ((size_t)q << 15));
    for (int i = tid; i < 8192; i += 256) {
        int cc = (i & 31) << 2;
        float4 v = p[i];
        v.x = (v.x - smean[cc])     * sscale[cc];
        v.y = (v.y - smean[cc + 1]) * sscale[cc + 1];
        v.z = (v.z - smean[cc + 2]) * sscale[cc + 2];
        v.w = (v.w - smean[cc + 3]) * sscale[cc + 3];
        p[i] = v;
    }
}

extern "C" void kernel_launch(void* const* d_in, const int* in_sizes, int n_in,
                              void* d_out, int out_size, void* d_ws, size_t ws_size,
                              hipStream_t stream) {
    (void)in_sizes; (void)n_in; (void)out_size; (void)ws_size;
    const float* inputs = (const float*)d_in[0];
    const float* hidden = (const float*)d_in[1];
    const float* W_ih   = (const float*)d_in[2];
    const float* b_ih   = (const float*)d_in[3];
    const float* W_hh   = (const float*)d_in[4];
    const float* b_hh   = (const float*)d_in[5];
    const float* W_lin  = (const float*)d_in[6];
    const float* b_lin  = (const float*)d_in[7];

    char* ws = (char*)d_ws;
    uint4*  wcp   = (uint4*)(ws + WS_WC);
    uint4*  w0p   = (uint4*)(ws + WS_W0);
    uint4*  wlp   = (uint4*)(ws + WS_WL);
    float4* bias0 = (float4*)(ws + WS_B0);
    float4* bcp   = (float4*)(ws + WS_BC);
    float*  stats = (float*)(ws + WS_ST);

    hipMemsetAsync(stats, 0, 262144, stream);
    pack_w0_kernel<<<161, 256, 0, stream>>>(W_ih, W_hh, W_lin, b_ih, b_hh, w0p, wlp, bias0);
    pack_wc_kernel<<<129, 256, 0, stream>>>(W_ih, W_hh, W_lin, b_ih, b_hh, b_lin, wcp, bcp);
    gru_kernel<<<64, 512, 0, stream>>>(inputs, hidden, wcp, w0p, bias0, bcp, (float*)d_out);
    ygemm_kernel<<<16384, 256, 0, stream>>>(wlp, b_lin, (float*)d_out, stats);
    norm_kernel<<<1024, 256, 0, stream>>>((float*)d_out, stats);
}